// Round 11
// baseline (157.642 us; speedup 1.0000x reference)
//
#include <hip/hip_runtime.h>
#include <math.h>

#define G_N   2048
#define NT    32
#define NP    32
#define NR    64
#define NRAY  (NT * NP)

// ---------------------------------------------------------------------------
// k_pre: one block per ray (grid 1024, 256 thr); each thread folds 8 gaussians
// for this ray and writes {A, B, Cf, alb} float4 records to d_ws (32 MB).
// q(t) = A*t^2 + B*t + Cf with c=-0.5*log2(e) prefolded and log2(opac) in Cf,
// so the hot kernel is exp2(q) <= opac < 1 (no overflow: P is PSD).
// ---------------------------------------------------------------------------
__global__ __launch_bounds__(256) void k_pre(
    const float* __restrict__ means, const float* __restrict__ scales,
    const float* __restrict__ rots, const float* __restrict__ opacs,
    const float* __restrict__ feats, const float* __restrict__ cam,
    float4* __restrict__ cf) {
  const int ray = blockIdx.x;
  const int ti  = ray >> 5;
  const int pj  = ray & 31;

  const float dth = (float)(M_PI / 2.0 / (NT - 1));
  const float dph = (float)(M_PI / (NP - 1));
  float sth, cth, sp, cp;
  sincosf((float)ti * dth, &sth, &cth);
  sincosf((float)(-M_PI / 2.0) + (float)pj * dph, &sp, &cp);
  const float dx = sth * cp, dy = sth * sp, dz = cth;
  const float dxx = dx*dx, dyy = dy*dy, dzz = dz*dz;
  const float dxy = 2.f*dx*dy, dxz = 2.f*dx*dz, dyz = 2.f*dy*dz;

  const float cx = cam[0], cy = cam[1], cz = cam[2];
  const float c      = -0.7213475204444817f;   // -0.5 * log2(e)
  const float l2e    = 1.4426950408889634f;
  const float n2l2e  = -2.8853900817779268f;   // -2*log2(e)
  const float SH_C0  = 0.28209479177387814f;

  const int tid = threadIdx.x;
  #pragma unroll
  for (int i = 0; i < G_N / 256; ++i) {
    int g = tid + i * 256;
    float i0 = __builtin_amdgcn_exp2f(n2l2e * scales[3*g+0]);
    float i1 = __builtin_amdgcn_exp2f(n2l2e * scales[3*g+1]);
    float i2 = __builtin_amdgcn_exp2f(n2l2e * scales[3*g+2]);

    float qw = rots[4*g+0], qx = rots[4*g+1], qy = rots[4*g+2], qz = rots[4*g+3];
    float inv = __builtin_amdgcn_rsqf(qw*qw + qx*qx + qy*qy + qz*qz);
    qw *= inv; qx *= inv; qy *= inv; qz *= inv;

    float R00 = 1.f - 2.f*(qy*qy + qz*qz), R01 = 2.f*(qx*qy - qw*qz), R02 = 2.f*(qx*qz + qw*qy);
    float R10 = 2.f*(qx*qy + qw*qz), R11 = 1.f - 2.f*(qx*qx + qz*qz), R12 = 2.f*(qy*qz - qw*qx);
    float R20 = 2.f*(qx*qz - qw*qy), R21 = 2.f*(qy*qz + qw*qx), R22 = 1.f - 2.f*(qx*qx + qy*qy);

    // c-prefolded precision matrix
    float p00 = c*(R00*R00*i0 + R01*R01*i1 + R02*R02*i2);
    float p11 = c*(R10*R10*i0 + R11*R11*i1 + R12*R12*i2);
    float p22 = c*(R20*R20*i0 + R21*R21*i1 + R02*0.f + R22*R22*i2);  // (see below)
    // NOTE: keep exact form; rewrite cleanly:
    p22 = c*(R20*R20*i0 + R21*R21*i1 + R22*R22*i2);
    float p01 = c*(R00*R10*i0 + R01*R11*i1 + R02*R12*i2);
    float p02 = c*(R00*R20*i0 + R01*R21*i1 + R02*R22*i2);
    float p12 = c*(R10*R20*i0 + R11*R21*i1 + R12*R22*i2);

    float ox = cx - means[3*g+0], oy = cy - means[3*g+1], oz = cz - means[3*g+2];
    float Px = p00*ox + p01*oy + p02*oz;      // = c * (P om)
    float Py = p01*ox + p11*oy + p12*oz;
    float Pz = p02*ox + p12*oy + p22*oz;
    float Cq = ox*Px + oy*Py + oz*Pz;         // = c * om^T P om

    float u  = __builtin_amdgcn_exp2f(-l2e * opacs[g]);
    float Cf = Cq - __builtin_amdgcn_logf(1.0f + u);   // + log2(sigmoid(op))

    float a0 = fmaxf(SH_C0*feats[3*g+0] + 0.5f, 0.f);
    float a1 = fmaxf(SH_C0*feats[3*g+1] + 0.5f, 0.f);
    float a2 = fmaxf(SH_C0*feats[3*g+2] + 0.5f, 0.f);
    float alb = (a0 + a1 + a2) * (1.0f/3.0f);

    float A = p00*dxx + p11*dyy + p22*dzz + p01*dxy + p02*dxz + p12*dyz;
    float B = 2.f * (Px*dx + Py*dy + Pz*dz);

    cf[(size_t)ray * G_N + g] = make_float4(A, B, Cf, alb);
  }
}

// ---------------------------------------------------------------------------
// k_main: one block per ray (grid 1024 -> 4 blocks/CU), 256 thr = 4 waves
// (16 waves/CU). lane = t sample; wave wv covers gaussians [wv*512, wv*512+512).
// Coefficients are wave-uniform -> scalar-pipe loads (s_load), ZERO LDS in the
// hot loop (r10 evidence: LDS broadcast return-bandwidth was the serialized
// resource TLP couldn't hide). ~6 inst/gaussian, tiny VGPR footprint.
// ---------------------------------------------------------------------------
__global__ __launch_bounds__(256, 4) void k_main(
    const float4* __restrict__ cf, float* __restrict__ out) {
  __shared__ float red[2][4][64];   // 2 KB

  const int tid  = threadIdx.x;
  const int ray  = blockIdx.x;
  const int wv   = tid >> 6;
  const int lane = tid & 63;

  const float tstep = 2.0f / 63.0f;
  const float t  = 0.5f + (float)lane * tstep;
  const float t2 = t * t;

  const float4* __restrict__ p = cf + (size_t)ray * G_N + wv * (G_N / 4);
  float d = 0.f, h = 0.f;
  #pragma unroll 8
  for (int g = 0; g < G_N / 4; ++g) {
    float4 e = p[g];
    float q = fmaf(e.y, t, e.x * t2) + e.z;   // A*t^2 + B*t + Cf
    float x = __builtin_amdgcn_exp2f(q);
    d += x;
    h = fmaf(x, e.w, h);
  }
  red[0][wv][lane] = d;
  red[1][wv][lane] = h;
  __syncthreads();

  if (tid < 64) {
    float D  = (red[0][0][tid] + red[0][1][tid]) + (red[0][2][tid] + red[0][3][tid]);
    float Rh = (red[1][0][tid] + red[1][1][tid]) + (red[1][2][tid] + red[1][3][tid]);
    const float step = 1.0f * 0.03125f;   // C_LIGHT * DELTA_T
    float s = D * step;
    float inc = s;
    #pragma unroll
    for (int off = 1; off < 64; off <<= 1) {
      float v = __shfl_up(inc, off, 64);
      if (tid >= off) inc += v;
    }
    float excl = inc - s;
    float T = __builtin_amdgcn_exp2f(-1.4426950408889634f * excl);
    float tv = 0.5f + (float)tid * tstep;
    const float dth = (float)(M_PI / 2.0 / (NT - 1));
    float sth = sinf((float)(ray >> 5) * dth);
    float res = Rh * T / (tv * tv + 1e-8f) * sth;
    out[tid * NRAY + ray] = res;
  }
}

// ---------------------------------------------------------------------------
// Histogram. One block per t bin; sum 1024 rays.
// ---------------------------------------------------------------------------
__global__ __launch_bounds__(256) void k_hist(const float* __restrict__ res,
                                              float* __restrict__ hist) {
  const int t = blockIdx.x;
  const int tid = threadIdx.x;
  float s = 0.f;
  #pragma unroll
  for (int rr = tid; rr < NRAY; rr += 256) s += res[t * NRAY + rr];
  #pragma unroll
  for (int off = 32; off > 0; off >>= 1) s += __shfl_down(s, off, 64);
  __shared__ float sm[4];
  if ((tid & 63) == 0) sm[tid >> 6] = s;
  __syncthreads();
  if (tid == 0) {
    const float dtdp = (float)((M_PI / 2.0 / NT) * (M_PI / NP));
    hist[t] = ((sm[0] + sm[1]) + (sm[2] + sm[3])) * dtdp;
  }
}

extern "C" void kernel_launch(void* const* d_in, const int* in_sizes, int n_in,
                              void* d_out, int out_size, void* d_ws, size_t ws_size,
                              hipStream_t stream) {
  const float* means  = (const float*)d_in[0];
  const float* scales = (const float*)d_in[1];
  const float* rots   = (const float*)d_in[2];
  const float* opacs  = (const float*)d_in[3];
  const float* feats  = (const float*)d_in[4];
  const float* cam    = (const float*)d_in[5];

  float4* cf  = (float4*)d_ws;          // 32 MB coefficient table
  float*  out = (float*)d_out;

  k_pre <<<NRAY, 256, 0, stream>>>(means, scales, rots, opacs, feats, cam, cf);
  k_main<<<NRAY, 256, 0, stream>>>(cf, out);
  k_hist<<<NR,   256, 0, stream>>>(out, out + NR * NRAY);
}

// Round 12
// 84.292 us; speedup vs baseline: 1.8702x; 1.8702x over previous
//
#include <hip/hip_runtime.h>
#include <math.h>

#define G_N   2048
#define NT    32
#define NP    32
#define NR    64
#define NRAY  (NT * NP)
#define PLANE 8196     // floats per ray-plane: 2048*4 + 4 pad -> +4 bank skew
#define QCULL -30.0f   // keep gaussian iff max_t q(t) > 2^-30 (contrib <= 1e-9)

// ---------------------------------------------------------------------------
// k_main: one block per 2 rays (grid 512 -> 2 blocks/CU), 512 thr = 8 waves
// (4 waves/SIMD). r10 evidence: hot loop is LDS-port bound (~12 cyc per
// ds_read_b128 x 4096/CU ~= 20us). Fix: cull per-(ray,g) in phase 0 -- the
// gaussians are angularly tiny (3*sigma ~ 0.15 rad vs pi-sr ray span), so only
// a few % survive max_t q(t) > QCULL. Ballot-compacted into the same
// bank-skewed planes; hot loop runs over n_act records only.
// ---------------------------------------------------------------------------
__global__ __launch_bounds__(512, 4) void k_main(
    const float* __restrict__ means, const float* __restrict__ scales,
    const float* __restrict__ rots, const float* __restrict__ opacs,
    const float* __restrict__ feats, const float* __restrict__ cam,
    float* __restrict__ out) {
  __shared__ float coef[2 * PLANE];   // 65,568 B (compacted records per ray)
  __shared__ float red[2][8][128];    // 8,192 B
  __shared__ int   nact[2];

  const int tid  = threadIdx.x;
  const int lane = tid & 63;
  const int wv   = tid >> 6;          // 0..7
  const int ray0 = blockIdx.x * 2;
  const int ti   = ray0 >> 5;
  const int pj0  = ray0 & 31;

  if (tid < 2) nact[tid] = 0;
  __syncthreads();

  const float dth = (float)(M_PI / 2.0 / (NT - 1));
  const float dph = (float)(M_PI / (NP - 1));
  float sth, cth;
  sincosf((float)ti * dth, &sth, &cth);
  const float dz = cth, dzz = dz * dz;

  float dX[2], dY[2], dXX[2], dYY[2], dXY[2], dXZ[2], dYZ[2];
  #pragma unroll
  for (int r = 0; r < 2; ++r) {
    float ph = (float)(-M_PI / 2.0) + (float)(pj0 + r) * dph;
    float sp, cp;
    sincosf(ph, &sp, &cp);
    float dx = sth * cp, dy = sth * sp;
    dX[r] = dx; dY[r] = dy;
    dXX[r] = dx * dx; dYY[r] = dy * dy;
    dXY[r] = 2.f * dx * dy; dXZ[r] = 2.f * dx * dz; dYZ[r] = 2.f * dy * dz;
  }

  const float cx = cam[0], cy = cam[1], cz = cam[2];
  const float c      = -0.7213475204444817f;   // -0.5 * log2(e)
  const float l2e    = 1.4426950408889634f;
  const float n2l2e  = -2.8853900817779268f;   // -2*log2(e)
  const float SH_C0  = 0.28209479177387814f;

  // ---------------- Phase 0: precompute + cull + ballot-compact ------------
  #pragma unroll
  for (int i = 0; i < G_N / 512; ++i) {
    int g = tid + i * 512;
    float i0 = __builtin_amdgcn_exp2f(n2l2e * scales[3*g+0]);
    float i1 = __builtin_amdgcn_exp2f(n2l2e * scales[3*g+1]);
    float i2 = __builtin_amdgcn_exp2f(n2l2e * scales[3*g+2]);

    float qw = rots[4*g+0], qx = rots[4*g+1], qy = rots[4*g+2], qz = rots[4*g+3];
    float inv = __builtin_amdgcn_rsqf(qw*qw + qx*qx + qy*qy + qz*qz);
    qw *= inv; qx *= inv; qy *= inv; qz *= inv;

    float R00 = 1.f - 2.f*(qy*qy + qz*qz), R01 = 2.f*(qx*qy - qw*qz), R02 = 2.f*(qx*qz + qw*qy);
    float R10 = 2.f*(qx*qy + qw*qz), R11 = 1.f - 2.f*(qx*qx + qz*qz), R12 = 2.f*(qy*qz - qw*qx);
    float R20 = 2.f*(qx*qz - qw*qy), R21 = 2.f*(qy*qz + qw*qx), R22 = 1.f - 2.f*(qx*qx + qy*qy);

    float p00 = c*(R00*R00*i0 + R01*R01*i1 + R02*R02*i2);
    float p11 = c*(R10*R10*i0 + R11*R11*i1 + R12*R12*i2);
    float p22 = c*(R20*R20*i0 + R21*R21*i1 + R22*R22*i2);
    float p01 = c*(R00*R10*i0 + R01*R11*i1 + R02*R12*i2);
    float p02 = c*(R00*R20*i0 + R01*R21*i1 + R02*R22*i2);
    float p12 = c*(R10*R20*i0 + R11*R21*i1 + R12*R22*i2);

    float ox = cx - means[3*g+0], oy = cy - means[3*g+1], oz = cz - means[3*g+2];
    float Px = p00*ox + p01*oy + p02*oz;      // = c * (P om)
    float Py = p01*ox + p11*oy + p12*oz;
    float Pz = p02*ox + p12*oy + p22*oz;
    float Cq = ox*Px + oy*Py + oz*Pz;         // = c * om^T P om

    float u  = __builtin_amdgcn_exp2f(-l2e * opacs[g]);
    float Cf = Cq - __builtin_amdgcn_logf(1.0f + u);   // + log2(sigmoid)

    float a0 = fmaxf(SH_C0*feats[3*g+0] + 0.5f, 0.f);
    float a1 = fmaxf(SH_C0*feats[3*g+1] + 0.5f, 0.f);
    float a2 = fmaxf(SH_C0*feats[3*g+2] + 0.5f, 0.f);
    float alb = (a0 + a1 + a2) * (1.0f/3.0f);

    #pragma unroll
    for (int r = 0; r < 2; ++r) {
      float A = p00*dXX[r] + p11*dYY[r] + p22*dzz + p01*dXY[r] + p02*dXZ[r] + p12*dYZ[r];
      float B = 2.f * (Px*dX[r] + Py*dY[r] + Pz*dz);
      // max over t in [0.5, 2.5]: A < 0 strictly (P positive definite)
      float tstar = fminf(2.5f, fmaxf(0.5f, -B / (2.f * A)));
      float qm = fmaf(fmaf(A, tstar, B), tstar, Cf);
      bool keep = qm > QCULL;
      unsigned long long m = __ballot(keep);
      int base;
      if (lane == 0) base = atomicAdd(&nact[r], __popcll(m));
      base = __shfl(base, 0, 64);
      if (keep) {
        int slot = base + __popcll(m & ((1ull << lane) - 1ull));
        *(float4*)&coef[r * PLANE + slot * 4] = make_float4(A, B, Cf, alb);
      }
    }
  }
  __syncthreads();

  // ---------------- Phase 1: hot loop over compacted records ----------------
  const int r  = lane >> 5;           // ray within pair
  const int ts = lane & 31;           // t-slot
  const float tstep = 2.0f / 63.0f;
  const float t0 = 0.5f + (float)ts * tstep;
  const float t1 = t0 + 32.f * tstep;

  const int n = nact[r];
  const float4* basep = (const float4*)&coef[r * PLANE];
  float d0 = 0.f, d1 = 0.f, h0 = 0.f, h1 = 0.f;
  for (int j = wv; j < n; j += 8) {
    float4 e = basep[j];
    float q0 = fmaf(fmaf(e.x, t0, e.y), t0, e.z);
    float q1 = fmaf(fmaf(e.x, t1, e.y), t1, e.z);
    float x0 = __builtin_amdgcn_exp2f(q0);
    float x1 = __builtin_amdgcn_exp2f(q1);
    d0 += x0; h0 = fmaf(x0, e.w, h0);
    d1 += x1; h1 = fmaf(x1, e.w, h1);
  }

  // ---------------- Phase 2: stash partials ----------------
  red[0][wv][r*64 + ts     ] = d0;  red[1][wv][r*64 + ts     ] = h0;
  red[0][wv][r*64 + ts + 32] = d1;  red[1][wv][r*64 + ts + 32] = h1;
  __syncthreads();

  // ---------------- Phase 3: reduce + scan + store (first 2 waves) ---------
  if (tid < 128) {
    const int rr = tid >> 6;
    const int t  = tid & 63;
    int idx = rr * 64 + t;
    float D  = ((red[0][0][idx] + red[0][1][idx]) + (red[0][2][idx] + red[0][3][idx]))
             + ((red[0][4][idx] + red[0][5][idx]) + (red[0][6][idx] + red[0][7][idx]));
    float Rh = ((red[1][0][idx] + red[1][1][idx]) + (red[1][2][idx] + red[1][3][idx]))
             + ((red[1][4][idx] + red[1][5][idx]) + (red[1][6][idx] + red[1][7][idx]));
    const float step = 1.0f * 0.03125f;   // C_LIGHT * DELTA_T
    float s = D * step;
    float inc = s;
    #pragma unroll
    for (int off = 1; off < 64; off <<= 1) {
      float v = __shfl_up(inc, off, 64);
      if (t >= off) inc += v;
    }
    float excl = inc - s;
    float T = __builtin_amdgcn_exp2f(-1.4426950408889634f * excl);
    float tv = 0.5f + (float)t * tstep;
    float res = Rh * T / (tv * tv + 1e-8f) * sth;
    out[t * NRAY + ray0 + rr] = res;
  }
}

// ---------------------------------------------------------------------------
// Histogram. One block per t bin; sum 1024 rays.
// ---------------------------------------------------------------------------
__global__ __launch_bounds__(256) void k_hist(const float* __restrict__ res,
                                              float* __restrict__ hist) {
  const int t = blockIdx.x;
  const int tid = threadIdx.x;
  float s = 0.f;
  #pragma unroll
  for (int rr = tid; rr < NRAY; rr += 256) s += res[t * NRAY + rr];
  #pragma unroll
  for (int off = 32; off > 0; off >>= 1) s += __shfl_down(s, off, 64);
  __shared__ float sm[4];
  if ((tid & 63) == 0) sm[tid >> 6] = s;
  __syncthreads();
  if (tid == 0) {
    const float dtdp = (float)((M_PI / 2.0 / NT) * (M_PI / NP));
    hist[t] = ((sm[0] + sm[1]) + (sm[2] + sm[3])) * dtdp;
  }
}

extern "C" void kernel_launch(void* const* d_in, const int* in_sizes, int n_in,
                              void* d_out, int out_size, void* d_ws, size_t ws_size,
                              hipStream_t stream) {
  const float* means  = (const float*)d_in[0];
  const float* scales = (const float*)d_in[1];
  const float* rots   = (const float*)d_in[2];
  const float* opacs  = (const float*)d_in[3];
  const float* feats  = (const float*)d_in[4];
  const float* cam    = (const float*)d_in[5];

  float* out = (float*)d_out;

  k_main<<<NRAY / 2, 512, 0, stream>>>(means, scales, rots, opacs, feats, cam, out);
  k_hist<<<NR,       256, 0, stream>>>(out, out + NR * NRAY);
}